// Round 7
// baseline (219.505 us; speedup 1.0000x reference)
//
#include <hip/hip_runtime.h>
#include <math.h>

// Problem constants
#define BATCH 8
#define NNODE 512
#define BN 4096           // BATCH*NNODE
#define DIM 128
#define HID 64
#define CAP 64            // max neighbors per row (mean ~20, 10 sigma margin)

__device__ __forceinline__ float sigmoidf(float x) {
  return 1.f / (1.f + expf(-x));
}
__device__ __forceinline__ float wave_sum(float v) {
  for (int off = 1; off < 64; off <<= 1) v += __shfl_xor(v, off, 64);
  return v;
}

// ---------------------------------------------------------------------------
// GIN block: 8 nodes/block, 2 rows/wave, fully register-resident.
// Neighbor indices+masks wave-loaded ONCE (1 coalesced load each) then
// broadcast per-iteration via shfl -> gather loop has no dependent index
// loads.  MLP dot products: agg in regs (col=lane), x[k] via shfl, W read
// coalesced from global (L1-hot across the 4 waves).  No barriers except
// the tail Ssum reduction.  zsum: 256-float LDS scratch.
// ---------------------------------------------------------------------------
template <int CIN, bool MASKED, int SOFF>
__device__ __forceinline__ void gin_block(
    float* zsum, int node0, const float* hin, const float* W1g,
    const float* b1, const float* W2g, const float* b2, float eps1,
    const int* csr, const int* cnt, const float* mask, float* hout,
    float* Ssum) {
  int tid = threadIdx.x, wave = tid >> 6, lane = tid & 63;
  int r0 = node0 + wave * 2, r1 = r0 + 1;
  int b9 = r0 & ~(NNODE - 1);
  int n0 = cnt[r0], n1 = cnt[r1];
  int jv0 = csr[r0 * CAP + lane];       // padded row: all 64 lanes valid
  int jv1 = csr[r1 * CAP + lane];
  float mv0, mv1;
  if (MASKED) {
    mv0 = (lane < n0) ? mask[b9 + jv0] : 0.f;
    mv1 = (lane < n1) ? mask[b9 + jv1] : 0.f;
  } else {
    mv0 = (lane < n0) ? 1.f : 0.f;
    mv1 = (lane < n1) ? 1.f : 0.f;
  }
  float mrow0 = MASKED ? mask[r0] : 1.f;
  float mrow1 = MASKED ? mask[r1] : 1.f;
  const float* h0p = hin + (size_t)r0 * CIN;
  const float* h1p = hin + (size_t)r1 * CIN;
  float a00 = eps1 * h0p[lane];
  float a01 = (CIN == 128) ? eps1 * h0p[lane + 64] : 0.f;
  float a10 = eps1 * h1p[lane];
  float a11 = (CIN == 128) ? eps1 * h1p[lane + 64] : 0.f;
  float s00 = 0.f, s01 = 0.f, s10 = 0.f, s11 = 0.f;
  int nm = n0 > n1 ? n0 : n1;
  for (int t = 0; t < nm; t++) {   // both rows interleaved: 2-4 loads in flight
    int j0 = __shfl(jv0, t, 64);
    int j1 = __shfl(jv1, t, 64);
    float m0 = __shfl(mv0, t, 64);   // 0 beyond n -> contributes nothing
    float m1 = __shfl(mv1, t, 64);
    const float* p0 = hin + (size_t)(b9 + j0) * CIN;
    const float* p1 = hin + (size_t)(b9 + j1) * CIN;
    s00 += m0 * p0[lane];
    s10 += m1 * p1[lane];
    if (CIN == 128) {
      s01 += m0 * p0[lane + 64];
      s11 += m1 * p1[lane + 64];
    }
  }
  a00 += mrow0 * s00;
  a10 += mrow1 * s10;
  if (CIN == 128) { a01 += mrow0 * s01; a11 += mrow1 * s11; }
  // MLP1: z[lane] = relu(b1[lane] + sum_k agg[k] * W1[k][lane])
  float z0 = b1[lane], z1 = z0;
  for (int k = 0; k < 64; k++) {
    float w = W1g[k * HID + lane];
    z0 += __shfl(a00, k, 64) * w;
    z1 += __shfl(a10, k, 64) * w;
  }
  if (CIN == 128) {
    for (int k = 0; k < 64; k++) {
      float w = W1g[(k + 64) * HID + lane];
      z0 += __shfl(a01, k, 64) * w;
      z1 += __shfl(a11, k, 64) * w;
    }
  }
  z0 = fmaxf(0.f, z0);
  z1 = fmaxf(0.f, z1);
  float c0 = b2[lane], c1v = c0;
  for (int k = 0; k < 64; k++) {
    float w = W2g[k * HID + lane];
    c0 += __shfl(z0, k, 64) * w;
    c1v += __shfl(z1, k, 64) * w;
  }
  float o0 = fmaxf(0.f, c0), o1 = fmaxf(0.f, c1v);
  hout[(size_t)r0 * HID + lane] = o0;
  hout[(size_t)r1 * HID + lane] = o1;
  zsum[wave * 64 + lane] = o0 + o1;
  __syncthreads();   // only barrier: Ssum tail reduction
  if (tid < 64) {
    float tot = zsum[tid] + zsum[64 + tid] + zsum[128 + tid] + zsum[192 + tid];
    atomicAdd(&Ssum[(node0 >> 9) * 320 + SOFF + tid], tot);
  }
}

// ---------------------------------------------------------------------------
// K1 (stage 1): blocks [0,1024): node MLPs (kappa + f0..f2), 16 nodes/block,
// register-resident (x in regs, shfl broadcast, W from global; no LDS, no
// barriers); [1024,2048): CSR build + degree; 2048: c1 + zero Ssum.
// ---------------------------------------------------------------------------
__global__ __launch_bounds__(256) void k_stage1(
    const float* X, const float* A, const float* cW1, const float* cb1,
    const float* cW2, const float* cb2, const float* fW1, const float* fb1,
    const float* fW2, const float* fb2, const float* wm_W1, const float* wm_b1,
    const float* wm_W2, const float* wm_b2, const float* wm_W3,
    const float* wm_b3, float* kap, float* f, float* c1_out, int* csr,
    int* cnt_arr, float* deg, float* Ssum) {
  __shared__ float sbuf[512];
  int bid = blockIdx.x;
  int tid = threadIdx.x, wave = tid >> 6, lane = tid & 63;
  if (bid < 1024) {
    int m = bid >> 8;   // 0=kappa, 1..3=f
    int grp = bid & 255;
    int nb = grp * 16 + wave * 4;
    const float* W1 = (m == 0) ? cW1 : fW1 + (size_t)(m - 1) * DIM * HID;
    const float* b1 = (m == 0) ? cb1 : fb1 + (m - 1) * HID;
    const float* W2 = (m == 0) ? cW2 : fW2 + (m - 1) * HID;
    float b2v = (m == 0) ? cb2[0] : fb2[m - 1];
    const float* xp = X + (size_t)nb * DIM;
    float x0a = xp[lane],       x0b = xp[64 + lane];
    float x1a = xp[128 + lane], x1b = xp[192 + lane];
    float x2a = xp[256 + lane], x2b = xp[320 + lane];
    float x3a = xp[384 + lane], x3b = xp[448 + lane];
    float bb = b1[lane];
    float acc0 = bb, acc1 = bb, acc2 = bb, acc3 = bb;
    for (int k = 0; k < 64; k++) {
      float w = W1[k * HID + lane];
      acc0 += __shfl(x0a, k, 64) * w;
      acc1 += __shfl(x1a, k, 64) * w;
      acc2 += __shfl(x2a, k, 64) * w;
      acc3 += __shfl(x3a, k, 64) * w;
    }
    for (int k = 0; k < 64; k++) {
      float w = W1[(k + 64) * HID + lane];
      acc0 += __shfl(x0b, k, 64) * w;
      acc1 += __shfl(x1b, k, 64) * w;
      acc2 += __shfl(x2b, k, 64) * w;
      acc3 += __shfl(x3b, k, 64) * w;
    }
    float w2l = W2[lane];
    float s0 = wave_sum(fmaxf(0.f, acc0) * w2l);
    float s1 = wave_sum(fmaxf(0.f, acc1) * w2l);
    float s2 = wave_sum(fmaxf(0.f, acc2) * w2l);
    float s3 = wave_sum(fmaxf(0.f, acc3) * w2l);
    if (lane < 4) {
      float sv = (lane == 0) ? s0 : (lane == 1) ? s1 : (lane == 2) ? s2 : s3;
      float s = sigmoidf(sv + b2v);
      int node = nb + lane;
      if (m == 0) kap[node] = s;
      else f[node * 3 + (m - 1)] = s;
    }
    return;
  }
  if (bid < 2048) {
    int r = (bid - 1024) * 4 + wave;
    const float* row = A + (size_t)r * NNODE;
    int base = r * CAP, cnt = 0;
    for (int c = 0; c < NNODE / 64; c++) {
      int j = c * 64 + lane;
      bool nz = (row[j] != 0.f);
      unsigned long long mb = __ballot(nz);
      if (nz) {
        int pos = __popcll(mb & ((1ull << lane) - 1ull));
        int slot = cnt + pos;
        if (slot < CAP) csr[base + slot] = j;
      }
      cnt += (int)__popcll(mb);
    }
    int cc = cnt < CAP ? cnt : CAP;
    if (lane >= cc) csr[base + lane] = 0;  // pad tail: all 64 slots valid
    if (lane == 0) {
      cnt_arr[r] = cc;
      deg[r] = (float)cnt;
    }
    return;
  }
  // zero Ssum (strictly precedes all stage2-4 atomics in stream order)
  for (int t = tid; t < BATCH * 320; t += 256) Ssum[t] = 0.f;
  // c1 = scalar weight-MLP(1.0)  (weights == c1*A since A is binary)
  float* u = sbuf;
  float* y = sbuf + 64;
  int l = tid;
  if (l < 64) u[l] = fmaxf(0.f, wm_W1[l] + wm_b1[l]);
  __syncthreads();
  if (l < 32) {
    float a = wm_b2[l];
    for (int k = 0; k < 64; k++) a += u[k] * wm_W2[k * 32 + l];
    y[l] = fmaxf(0.f, a);
  }
  __syncthreads();
  if (l == 0) {
    float a = wm_b3[0];
    for (int k = 0; k < 32; k++) a += y[k] * wm_W3[k];
    *c1_out = sigmoidf(a);
  }
}

// ---------------------------------------------------------------------------
// K2 (stage 2): [0,1024): curvature pass1 + gamma terms, wave/row;
// [1024,1032): top-k rank masks; [1032,1544): GIN layer 0 (X, CIN=128,
// h1 colsums); [1544,1608): X column sums -> Ssum[:,0:128].
// GG[r*12]: [gamma_i, df_i, fi*df_i] i=0..2, then s1_i.
// ---------------------------------------------------------------------------
__global__ __launch_bounds__(256) void k_stage2(
    const float* X, const float* f, const float* kap, const int* p_ptr,
    const int* csr, const int* cnt, const float* deg, const float* c1p,
    const float* g0_W1, const float* g0_b1, const float* g0_W2,
    const float* g0_b2, const float* gin_eps, float* GG, float* M1, float* M2,
    float* h1, float* Ssum) {
  __shared__ float sbuf[512];
  int bid = blockIdx.x;
  int wave = threadIdx.x >> 6, lane = threadIdx.x & 63;
  if (bid < 1024) {
    int r = bid * 4 + wave;
    int b9 = r & ~(NNODE - 1);
    int n = cnt[r];
    int j = csr[r * CAP + lane];
    float f0 = 0.f, f1 = 0.f, f2 = 0.f;
    if (lane < n) {
      const float* fj = f + (size_t)(b9 + j) * 3;
      f0 = fj[0]; f1 = fj[1]; f2 = fj[2];
    }
    float s10 = wave_sum(f0), s11 = wave_sum(f1), s12 = wave_sum(f2);
    float s20 = wave_sum(f0 * f0), s21 = wave_sum(f1 * f1),
          s22 = wave_sum(f2 * f2);
    if (lane < 3) {
      float s1 = (lane == 0) ? s10 : (lane == 1) ? s11 : s12;
      float s2 = (lane == 0) ? s20 : (lane == 1) ? s21 : s22;
      float c1 = *c1p, dA = deg[r];
      float fi = f[r * 3 + lane];
      float gamma = 0.5f * c1 * (fi * fi * dA - 2.f * fi * s1 + s2);
      float df = c1 * (fi * dA - s1);
      float* o = GG + (size_t)r * 12;
      o[lane * 3 + 0] = gamma;
      o[lane * 3 + 1] = df;
      o[lane * 3 + 2] = fi * df;
      o[9 + lane] = s1;
    }
    return;
  }
  if (bid < 1024 + BATCH) {
    int b = bid - 1024;
    float* ks = sbuf;
    for (int t = threadIdx.x; t < NNODE; t += 256) ks[t] = kap[b * NNODE + t];
    __syncthreads();
    int p = *p_ptr;
    int num1 = (NNODE * p) / 100;
    int num2 = (NNODE * 2 * p) / 100;
    int numm = num1 > num2 ? num1 : num2;
    for (int i = threadIdx.x; i < NNODE; i += 256) {
      float v = ks[i];
      int rank = 0;
      for (int j = 0; j < NNODE; j++) {
        float u = ks[j];
        rank += (u > v) || (u == v && j < i);  // jax.lax.top_k tie-break
      }
      M1[b * NNODE + i] = (rank < num1) ? 0.f : 1.f;
      M2[b * NNODE + i] = (rank < numm) ? 0.f : 1.f;
    }
    return;
  }
  if (bid < 1024 + BATCH + 512) {
    gin_block<DIM, false, 128>(sbuf, (bid - 1024 - BATCH) * 8, X, g0_W1,
                               g0_b1, g0_W2, g0_b2, 1.f + gin_eps[0], csr,
                               cnt, nullptr, h1, Ssum);
    return;
  }
  // X column sums: 64 blocks, each a batch-slice of 64 rows x 128 cols
  int idx = bid - (1024 + BATCH + 512);
  int b = idx >> 3, sl = idx & 7;
  int col = threadIdx.x & 127, rg = threadIdx.x >> 7;  // 2 row-groups
  const float* xb = X + (size_t)b * NNODE * DIM;
  int n0 = sl * 64;
  float s = 0.f;
  for (int n = n0 + rg; n < n0 + 64; n += 2) s += xb[(size_t)n * DIM + col];
  sbuf[threadIdx.x] = s;
  __syncthreads();
  if (threadIdx.x < 128)
    atomicAdd(&Ssum[b * 320 + col], sbuf[threadIdx.x] + sbuf[threadIdx.x + 128]);
}

// ---------------------------------------------------------------------------
// K3 (stage 3): [0,1024): curvature pass2 -> loss_part[bid];
// [1024,1536): GIN layer 1 (mask M1; h2 colsums -> Ssum[:,192:256]).
// ---------------------------------------------------------------------------
__global__ __launch_bounds__(256) void k_stage3(
    const float* f, const float* kap, const float* deg, const float* GG,
    const int* csr, const int* cnt, const float* c1p, float* loss_part,
    const float* h1, const float* g1_W1, const float* g1_b1,
    const float* g1_W2, const float* g1_b2, const float* gin_eps,
    const float* M1, float* h2, float* Ssum) {
  __shared__ float sbuf[260];
  int bid = blockIdx.x;
  int wave = threadIdx.x >> 6, lane = threadIdx.x & 63;
  if (bid < 1024) {
    int r = bid * 4 + wave;
    int b9 = r & ~(NNODE - 1);
    int n = cnt[r];
    int j = csr[r * CAP + lane];
    float T[9];
    for (int c = 0; c < 9; c++) T[c] = 0.f;
    if (lane < n) {
      const float4* g = (const float4*)(GG + (size_t)(b9 + j) * 12);
      float4 g0 = g[0], g1 = g[1], g2 = g[2];
      T[0] = g0.x; T[1] = g0.y; T[2] = g0.z;
      T[3] = g0.w; T[4] = g1.x; T[5] = g1.y;
      T[6] = g1.z; T[7] = g1.w; T[8] = g2.x;
    }
    for (int c = 0; c < 9; c++) T[c] = wave_sum(T[c]);
    float kp = kap[r];
    float local = 0.f;
    if (lane < 3) {
      int i = lane;
      float c1 = *c1p, dA = deg[r];
      const float* o = GG + (size_t)r * 12;
      float fi = f[r * 3 + i];
      float s1 = o[9 + i];
      float gamma = o[i * 3 + 0], df = o[i * 3 + 1];
      float dgamma = c1 * (gamma * dA - T[i * 3 + 0]);
      float gfd = 0.5f * c1 * (fi * df * dA - fi * T[i * 3 + 1] - df * s1 +
                               T[i * 3 + 2]);
      float gamma2 = 0.5f * dgamma - gfd;
      local = fmaxf(0.f, kp * gamma - gamma2);
    }
    if (lane == 0) local -= 3.f * kp;  // "- kappa.sum()" once per f_i
    local = wave_sum(local);
    if (lane == 0) sbuf[256 + wave] = local;
    __syncthreads();
    if (threadIdx.x == 0)
      loss_part[bid] = sbuf[256] + sbuf[257] + sbuf[258] + sbuf[259];
    return;
  }
  gin_block<HID, true, 192>(sbuf, (bid - 1024) * 8, h1, g1_W1, g1_b1, g1_W2,
                            g1_b2, 1.f + gin_eps[1], csr, cnt, M1, h2, Ssum);
}

// ---------------------------------------------------------------------------
// K4: GIN layer 2 (mask M2 == M1*M2 by top-k nesting; h3 colsums -> 256:320).
// ---------------------------------------------------------------------------
__global__ __launch_bounds__(256) void k_stage4(
    const float* h2, const float* g2_W1, const float* g2_b1,
    const float* g2_W2, const float* g2_b2, const float* gin_eps,
    const int* csr, const int* cnt, const float* M2, float* h3, float* Ssum) {
  __shared__ float sbuf[256];
  gin_block<HID, true, 256>(sbuf, blockIdx.x * 8, h2, g2_W1, g2_b1, g2_W2,
                            g2_b2, 1.f + gin_eps[2], csr, cnt, M2, h3, Ssum);
}

// ---------------------------------------------------------------------------
// K5: tiny readout: out[b] = Ssum[b] @ out_W + out_b; block 0 reduces loss.
// ---------------------------------------------------------------------------
__global__ __launch_bounds__(320) void k_out(
    const float* Ssum, const float* out_W, const float* out_b,
    const float* loss_part, float* out) {
  int b = blockIdx.x;
  int t = threadIdx.x;  // 320
  __shared__ float S[320];
  __shared__ float wpart[5];
  S[t] = Ssum[b * 320 + t];
  if (b == 0) {  // loss reduction: 1024 partials
    float ls = 0.f;
    for (int i = t; i < 1024; i += 320) ls += loss_part[i];
    ls = wave_sum(ls);
    if ((t & 63) == 0) wpart[t >> 6] = ls;
  }
  __syncthreads();
  if (t < 10) {
    float acc = out_b[t];
    for (int d = 0; d < 320; d++) acc += S[d] * out_W[d * 10 + t];
    out[b * 10 + t] = acc;
  }
  if (b == 0 && t == 0) {
    float ls = 0.f;
    for (int w = 0; w < 5; w++) ls += wpart[w];
    out[80] = ls;
  }
}

// ---------------------------------------------------------------------------
extern "C" void kernel_launch(void* const* d_in, const int* in_sizes, int n_in,
                              void* d_out, int out_size, void* d_ws,
                              size_t ws_size, hipStream_t stream) {
  const float* X       = (const float*)d_in[0];
  const float* A       = (const float*)d_in[1];
  const int*   p       = (const int*)d_in[2];
  const float* curv_W1 = (const float*)d_in[3];
  const float* curv_b1 = (const float*)d_in[4];
  const float* curv_W2 = (const float*)d_in[5];
  const float* curv_b2 = (const float*)d_in[6];
  const float* wm_W1   = (const float*)d_in[7];
  const float* wm_b1   = (const float*)d_in[8];
  const float* wm_W2   = (const float*)d_in[9];
  const float* wm_b2   = (const float*)d_in[10];
  const float* wm_W3   = (const float*)d_in[11];
  const float* wm_b3   = (const float*)d_in[12];
  const float* fn_W1   = (const float*)d_in[13];
  const float* fn_b1   = (const float*)d_in[14];
  const float* fn_W2   = (const float*)d_in[15];
  const float* fn_b2   = (const float*)d_in[16];
  const float* gin_eps = (const float*)d_in[17];
  const float* g0_W1   = (const float*)d_in[18];
  const float* g0_b1   = (const float*)d_in[19];
  const float* g0_W2   = (const float*)d_in[20];
  const float* g0_b2   = (const float*)d_in[21];
  const float* g1_W1   = (const float*)d_in[22];
  const float* g1_b1   = (const float*)d_in[23];
  const float* g1_W2   = (const float*)d_in[24];
  const float* g1_b2   = (const float*)d_in[25];
  const float* g2_W1   = (const float*)d_in[26];
  const float* g2_b1   = (const float*)d_in[27];
  const float* g2_W2   = (const float*)d_in[28];
  const float* g2_b2   = (const float*)d_in[29];
  const float* out_W   = (const float*)d_in[30];
  const float* out_b   = (const float*)d_in[31];
  float* out = (float*)d_out;

  float* ws = (float*)d_ws;
  size_t o = 0;
  float* loss_part = ws + o; o += 1024;
  float* c1       = ws + o; o += 16;
  float* Ssum     = ws + o; o += BATCH * 320 + 16;
  float* kap      = ws + o; o += BN;
  float* f        = ws + o; o += (size_t)BN * 3 + 16;
  float* deg      = ws + o; o += BN;
  float* M1       = ws + o; o += BN;
  float* M2       = ws + o; o += BN;
  float* GG       = ws + o; o += (size_t)BN * 12;
  float* h1       = ws + o; o += (size_t)BN * HID;
  float* h2       = ws + o; o += (size_t)BN * HID;
  float* h3       = ws + o; o += (size_t)BN * HID;
  int* cnt  = (int*)(ws + o); o += BN;
  int* csr  = (int*)(ws + o); o += (size_t)BN * CAP;

  k_stage1<<<2049, 256, 0, stream>>>(
      X, A, curv_W1, curv_b1, curv_W2, curv_b2, fn_W1, fn_b1, fn_W2, fn_b2,
      wm_W1, wm_b1, wm_W2, wm_b2, wm_W3, wm_b3, kap, f, c1, csr, cnt, deg,
      Ssum);
  k_stage2<<<1024 + BATCH + 512 + 64, 256, 0, stream>>>(
      X, f, kap, p, csr, cnt, deg, c1, g0_W1, g0_b1, g0_W2, g0_b2, gin_eps,
      GG, M1, M2, h1, Ssum);
  k_stage3<<<1536, 256, 0, stream>>>(f, kap, deg, GG, csr, cnt, c1, loss_part,
                                     h1, g1_W1, g1_b1, g1_W2, g1_b2, gin_eps,
                                     M1, h2, Ssum);
  k_stage4<<<512, 256, 0, stream>>>(h2, g2_W1, g2_b1, g2_W2, g2_b2, gin_eps,
                                    csr, cnt, M2, h3, Ssum);
  k_out<<<BATCH, 320, 0, stream>>>(Ssum, out_W, out_b, loss_part, out);
}